// Round 1
// baseline (348.919 us; speedup 1.0000x reference)
//
#include <hip/hip_runtime.h>
#include <math.h>

// Problem constants
#define NB   4      // batch
#define LQ   512
#define LK   512
#define DM   512    // d_model
#define NH   8      // heads
#define DQ   64     // head dim
#define NL   8      // labels

// Workspace layout (floats)
#define OFF_Q    0
#define OFF_K    1048576
#define OFF_VT   (2*1048576)
#define OFF_ATTN (3*1048576)
#define OFF_S    (OFF_ATTN + 8388608)   // s[h,b,q,l]
#define OFF_T    (OFF_S + 131072)       // t[h,b,q,l]
#define OFF_H    (OFF_T + 131072)       // head outputs (b,q,h*64+d)
// total floats = OFF_H + 1048576 = 12,845,056  (~51.4 MB)

// ---------------------------------------------------------------------------
// Generic 64x64-tile fp32 GEMM body: C_tile = A(64xK, ld=lda) * B(64xK, ld=ldb)^T
// A rows and B rows are both contiguous over K ("A @ B^T" with B row-major NxK).
// 256 threads, each computes 4x4.  LDS k-major for broadcast-friendly reads.
// ---------------------------------------------------------------------------
__device__ __forceinline__ void gemm64(const float* __restrict__ Ag,
                                       const float* __restrict__ Bg,
                                       int K, int lda, int ldb,
                                       float acc[4][4],
                                       float (*As)[64], float (*Bs)[64]) {
    const int tid = threadIdx.x;
    const int tx = tid & 15, ty = tid >> 4;
    const int lr = tid >> 2;            // 0..63 : row loaded
    const int lc = (tid & 3) * 4;       // k-offset of the float4

    for (int k0 = 0; k0 < K; k0 += 16) {
        const float4 av = *reinterpret_cast<const float4*>(Ag + (size_t)lr * lda + k0 + lc);
        const float4 bv = *reinterpret_cast<const float4*>(Bg + (size_t)lr * ldb + k0 + lc);
        __syncthreads();   // protect previous iteration's LDS reads
        As[lc + 0][lr] = av.x; As[lc + 1][lr] = av.y; As[lc + 2][lr] = av.z; As[lc + 3][lr] = av.w;
        Bs[lc + 0][lr] = bv.x; Bs[lc + 1][lr] = bv.y; Bs[lc + 2][lr] = bv.z; Bs[lc + 3][lr] = bv.w;
        __syncthreads();
#pragma unroll
        for (int kk = 0; kk < 16; ++kk) {
            const float4 a = *reinterpret_cast<const float4*>(&As[kk][ty * 4]);
            const float4 b = *reinterpret_cast<const float4*>(&Bs[kk][tx * 4]);
            const float a4[4] = {a.x, a.y, a.z, a.w};
            const float b4[4] = {b.x, b.y, b.z, b.w};
#pragma unroll
            for (int i = 0; i < 4; ++i)
#pragma unroll
                for (int j = 0; j < 4; ++j)
                    acc[i][j] = fmaf(a4[i], b4[j], acc[i][j]);
        }
    }
}

// ---------------------------------------------------------------------------
// Projection GEMM:  C[m, n] = sum_d A[m,d] * W[n,d] (+ bias[n])
// transposedPerB: store as Vt[b][n][m%512] instead (for the V projection).
// ---------------------------------------------------------------------------
__global__ __launch_bounds__(256) void proj_kernel(const float* __restrict__ A,
                                                   const float* __restrict__ W,
                                                   const float* __restrict__ bias,
                                                   float* __restrict__ C,
                                                   int transposedPerB) {
    __shared__ float As[16][64], Bs[16][64];
    float acc[4][4] = {};
    const int m0 = blockIdx.x * 64, n0 = blockIdx.y * 64;
    gemm64(A + (size_t)m0 * DM, W + (size_t)n0 * DM, DM, DM, DM, acc, As, Bs);
    const int tx = threadIdx.x & 15, ty = threadIdx.x >> 4;
    if (!transposedPerB) {
#pragma unroll
        for (int i = 0; i < 4; ++i) {
            const int row = m0 + ty * 4 + i;
#pragma unroll
            for (int j = 0; j < 4; ++j) {
                const int col = n0 + tx * 4 + j;
                const float bv = bias ? bias[col] : 0.0f;
                C[(size_t)row * DM + col] = acc[i][j] + bv;
            }
        }
    } else {
        const int b = m0 >> 9;           // 512 rows per batch, tiles never straddle
        const int kl = m0 & 511;
#pragma unroll
        for (int i = 0; i < 4; ++i)
#pragma unroll
            for (int j = 0; j < 4; ++j)
                C[(size_t)b * (DM * LK) + (size_t)(n0 + tx * 4 + j) * LK + (kl + ty * 4 + i)] = acc[i][j];
    }
}

// ---------------------------------------------------------------------------
// Batched QK^T:  qk[z=(h*4+b)][q][k] = sum_d Q[b][q][h*64+d] * K[b][k][h*64+d]
// Written RAW (unscaled, no rel term) into the d_out weights region.
// ---------------------------------------------------------------------------
__global__ __launch_bounds__(256) void qk_kernel(const float* __restrict__ Qb,
                                                 const float* __restrict__ Kb,
                                                 float* __restrict__ Cw) {
    __shared__ float As[16][64], Bs[16][64];
    float acc[4][4] = {};
    const int z = blockIdx.z, h = z >> 2, b = z & 3;
    const int m0 = blockIdx.x * 64, n0 = blockIdx.y * 64;
    const float* Ag = Qb + (size_t)b * (LQ * DM) + (size_t)m0 * DM + h * DQ;
    const float* Bg = Kb + (size_t)b * (LK * DM) + (size_t)n0 * DM + h * DQ;
    gemm64(Ag, Bg, DQ, DM, DM, acc, As, Bs);
    const int tx = threadIdx.x & 15, ty = threadIdx.x >> 4;
    float* Crow = Cw + (size_t)z * (LQ * LK);
#pragma unroll
    for (int i = 0; i < 4; ++i)
#pragma unroll
        for (int j = 0; j < 4; ++j)
            Crow[(size_t)(m0 + ty * 4 + i) * LK + (n0 + tx * 4 + j)] = acc[i][j];
}

// ---------------------------------------------------------------------------
// s[h,b,q,l] = sum_d Q[b][q][h*64+d] * b_ks[l][d]
// ---------------------------------------------------------------------------
__global__ __launch_bounds__(64) void rels_kernel(const float* __restrict__ Qb,
                                                  const float* __restrict__ b_ks,
                                                  float* __restrict__ sbuf) {
    __shared__ float qS[DM], bS[NL * DQ];
    const int bq = blockIdx.x;           // b*512 + q
    const int b = bq >> 9, q = bq & 511;
    const int tid = threadIdx.x;
    const float4* qG = reinterpret_cast<const float4*>(Qb + (size_t)bq * DM);
    const float4* bG = reinterpret_cast<const float4*>(b_ks);
#pragma unroll
    for (int i = tid; i < 128; i += 64) {
        reinterpret_cast<float4*>(qS)[i] = qG[i];
        reinterpret_cast<float4*>(bS)[i] = bG[i];
    }
    __syncthreads();
    const int h = tid >> 3, l = tid & 7;
    float s = 0.0f;
#pragma unroll
    for (int d = 0; d < DQ; ++d) s = fmaf(qS[h * DQ + d], bS[l * DQ + d], s);
    sbuf[((size_t)(h * NB + b) * LQ + q) * NL + l] = s;
}

// ---------------------------------------------------------------------------
// Block reductions (256 threads = 4 waves)
// ---------------------------------------------------------------------------
__device__ __forceinline__ float blockMax(float v, volatile float* red) {
#pragma unroll
    for (int o = 32; o > 0; o >>= 1) v = fmaxf(v, __shfl_down(v, o, 64));
    __syncthreads();
    if ((threadIdx.x & 63) == 0) red[threadIdx.x >> 6] = v;
    __syncthreads();
    return fmaxf(fmaxf(red[0], red[1]), fmaxf(red[2], red[3]));
}
__device__ __forceinline__ float blockSum(float v, volatile float* red) {
#pragma unroll
    for (int o = 32; o > 0; o >>= 1) v += __shfl_down(v, o, 64);
    __syncthreads();
    if ((threadIdx.x & 63) == 0) red[threadIdx.x >> 6] = v;
    __syncthreads();
    return (red[0] + red[1]) + (red[2] + red[3]);
}

// ---------------------------------------------------------------------------
// Fused rel-score + mask + softmax + t for all 8 heads of one (b,q) row.
// edge_mask row staged ONCE in LDS ([l][k] layout, conflict-free reads).
// weights region: reads raw qk, overwrites with (qk + qkr)/8 (pre-mask values).
// attn: softmaxed, masked-to-zero probabilities.  t[h,b,q,l] = sum_k attn*em.
// ---------------------------------------------------------------------------
__global__ __launch_bounds__(256) void softmax_kernel(const float* __restrict__ em,
                                                      const float* __restrict__ pad,
                                                      const float* __restrict__ sbuf,
                                                      float* __restrict__ weights,
                                                      float* __restrict__ attn,
                                                      float* __restrict__ tbuf) {
    __shared__ float emS[NL * LK];     // [l][k]  16 KB
    __shared__ float maskS[LK];        // 1.0 if masked
    __shared__ float red[4];
    __shared__ float tred[4 * NL];
    const int tid = threadIdx.x;
    const int bq = blockIdx.x, b = bq >> 9, q = bq & 511;

    // Stage edge_mask row: global [k][l] (l contiguous) -> LDS [l][k]
    {
        const float4* g = reinterpret_cast<const float4*>(em + (size_t)bq * (LK * NL));
#pragma unroll
        for (int i = 0; i < 4; ++i) {
            const int idx4 = tid + 256 * i;          // float4 index, 0..1023
            const float4 v = g[idx4];
            const int k = idx4 >> 1;
            const int l0 = (idx4 & 1) * 4;
            emS[(l0 + 0) * LK + k] = v.x;
            emS[(l0 + 1) * LK + k] = v.y;
            emS[(l0 + 2) * LK + k] = v.z;
            emS[(l0 + 3) * LK + k] = v.w;
        }
    }
    __syncthreads();
    // relation mask: masked iff em.sum(-1)==0 AND padding==1   (exact fp arith)
#pragma unroll
    for (int r = 0; r < 2; ++r) {
        const int k = tid + 256 * r;
        float es = 0.0f;
#pragma unroll
        for (int l = 0; l < NL; ++l) es += emS[l * LK + k];
        const float pv = pad[(size_t)bq * LK + k];
        maskS[k] = ((es + 1.0f - pv) == 0.0f) ? 1.0f : 0.0f;
    }
    __syncthreads();

    for (int h = 0; h < NH; ++h) {
        const int z = h * NB + b;
        const size_t rowbase = ((size_t)z * LQ + q) * LK;
        float sv[NL];
        const float* sp = sbuf + ((size_t)z * LQ + q) * NL;
#pragma unroll
        for (int l = 0; l < NL; ++l) sv[l] = sp[l];

        float m[2];
#pragma unroll
        for (int r = 0; r < 2; ++r) {
            const int k = tid + 256 * r;
            const float qkv = weights[rowbase + k];
            float rel = 0.0f;
#pragma unroll
            for (int l = 0; l < NL; ++l) rel = fmaf(emS[l * LK + k], sv[l], rel);
            const float wv = (qkv + rel) * 0.125f;
            weights[rowbase + k] = wv;                    // pre-mask weights output
            m[r] = (maskS[k] > 0.5f) ? -INFINITY : wv;
        }
        const float rowmax = blockMax(fmaxf(m[0], m[1]), red);
        float e[2];
        e[0] = __expf(m[0] - rowmax);                     // masked -> exp(-inf)=0
        e[1] = __expf(m[1] - rowmax);
        const float denom = blockSum(e[0] + e[1], red);
        const float inv = 1.0f / denom;

        float tl[NL] = {};
#pragma unroll
        for (int r = 0; r < 2; ++r) {
            const int k = tid + 256 * r;
            const float a = e[r] * inv;
            attn[rowbase + k] = a;
#pragma unroll
            for (int l = 0; l < NL; ++l) tl[l] = fmaf(a, emS[l * LK + k], tl[l]);
        }
        // reduce tl[8] across block
#pragma unroll
        for (int l = 0; l < NL; ++l)
#pragma unroll
            for (int o = 32; o > 0; o >>= 1) tl[l] += __shfl_down(tl[l], o, 64);
        __syncthreads();
        if ((tid & 63) == 0) {
            const int wid = tid >> 6;
#pragma unroll
            for (int l = 0; l < NL; ++l) tred[wid * NL + l] = tl[l];
        }
        __syncthreads();
        if (tid < NL) {
            const float t = tred[tid] + tred[NL + tid] + tred[2 * NL + tid] + tred[3 * NL + tid];
            tbuf[((size_t)z * LQ + q) * NL + tid] = t;
        }
    }
}

// ---------------------------------------------------------------------------
// qv + qvr:  hbuf[b][q][h*64+d] = sum_k attn[z][q][k]*Vt[b][h*64+d][k]
//                               + sum_l t[z][q][l]*b_vs[l][d]
// ---------------------------------------------------------------------------
__global__ __launch_bounds__(256) void qv_kernel(const float* __restrict__ attn,
                                                 const float* __restrict__ Vt,
                                                 const float* __restrict__ tbuf,
                                                 const float* __restrict__ b_vs,
                                                 float* __restrict__ hbuf) {
    __shared__ float As[16][64], Bs[16][64];
    float acc[4][4] = {};
    const int z = blockIdx.z, h = z >> 2, b = z & 3;
    const int m0 = blockIdx.x * 64;      // n0 = 0, N=64
    const float* Ag = attn + (size_t)z * (LQ * LK) + (size_t)m0 * LK;
    const float* Bg = Vt + (size_t)b * (DM * LK) + (size_t)(h * DQ) * LK;
    gemm64(Ag, Bg, LK, LK, LK, acc, As, Bs);
    const int tx = threadIdx.x & 15, ty = threadIdx.x >> 4;
#pragma unroll
    for (int i = 0; i < 4; ++i) {
        const int qrow = m0 + ty * 4 + i;
        const float* t8 = tbuf + ((size_t)z * LQ + qrow) * NL;
        float t[NL];
#pragma unroll
        for (int l = 0; l < NL; ++l) t[l] = t8[l];
#pragma unroll
        for (int j = 0; j < 4; ++j) {
            const int d = tx * 4 + j;
            float qvr = 0.0f;
#pragma unroll
            for (int l = 0; l < NL; ++l) qvr = fmaf(t[l], b_vs[l * DQ + d], qvr);
            hbuf[(size_t)b * (LQ * DM) + (size_t)qrow * DM + h * DQ + d] = acc[i][j] + qvr;
        }
    }
}

// ---------------------------------------------------------------------------
extern "C" void kernel_launch(void* const* d_in, const int* in_sizes, int n_in,
                              void* d_out, int out_size, void* d_ws, size_t ws_size,
                              hipStream_t stream) {
    const float* q     = (const float*)d_in[0];
    const float* k     = (const float*)d_in[1];
    const float* em    = (const float*)d_in[2];
    const float* pad   = (const float*)d_in[3];
    const float* w_q_w = (const float*)d_in[4];
    const float* w_q_b = (const float*)d_in[5];
    const float* w_k   = (const float*)d_in[6];
    const float* w_v   = (const float*)d_in[7];
    const float* w_h_w = (const float*)d_in[8];
    const float* w_h_b = (const float*)d_in[9];
    const float* b_ks  = (const float*)d_in[10];
    const float* b_vs  = (const float*)d_in[11];

    float* out     = (float*)d_out;                 // (B, LQ, DM)
    float* weights = out + (size_t)NB * LQ * DM;    // (H*B, LQ, LK)
    float* ws = (float*)d_ws;
    float* Qb   = ws + OFF_Q;
    float* Kb   = ws + OFF_K;
    float* Vt   = ws + OFF_VT;
    float* Attn = ws + OFF_ATTN;
    float* Sb   = ws + OFF_S;
    float* Tb   = ws + OFF_T;
    float* Hb   = ws + OFF_H;

    const dim3 blk(256);
    proj_kernel<<<dim3(32, 8), blk, 0, stream>>>(q, w_q_w, w_q_b, Qb, 0);
    proj_kernel<<<dim3(32, 8), blk, 0, stream>>>(k, w_k, nullptr, Kb, 0);
    proj_kernel<<<dim3(32, 8), blk, 0, stream>>>(k, w_v, nullptr, Vt, 1);
    qk_kernel<<<dim3(8, 8, 32), blk, 0, stream>>>(Qb, Kb, weights);
    rels_kernel<<<dim3(NB * LQ), dim3(64), 0, stream>>>(Qb, b_ks, Sb);
    softmax_kernel<<<dim3(NB * LQ), blk, 0, stream>>>(em, pad, Sb, weights, Attn, Tb);
    qv_kernel<<<dim3(8, 1, 32), blk, 0, stream>>>(Attn, Vt, Tb, b_vs, Hb);
    proj_kernel<<<dim3(32, 8), blk, 0, stream>>>(Hb, w_h_w, w_h_b, out, 0);
}

// Round 2
// 215.509 us; speedup vs baseline: 1.6190x; 1.6190x over previous
//
#include <hip/hip_runtime.h>
#include <math.h>

#define NB 4
#define LQ 512
#define LK 512
#define DM 512
#define NH 8
#define DQ 64
#define NL 8

typedef short bf16x8 __attribute__((ext_vector_type(8)));
typedef float f32x4 __attribute__((ext_vector_type(4)));

__device__ __forceinline__ unsigned short f2bf(float x) {
    unsigned u = __float_as_uint(x);
    u += 0x7fff + ((u >> 16) & 1);          // RNE
    return (unsigned short)(u >> 16);
}
__device__ __forceinline__ float bf2f(unsigned x) {
    return __uint_as_float(x << 16);
}

// async global->LDS, 16B per lane. LDS dest is wave-uniform base + lane*16.
__device__ __forceinline__ void gld16(const void* g, void* l) {
    __builtin_amdgcn_global_load_lds(
        (const __attribute__((address_space(1))) void*)g,
        (__attribute__((address_space(3))) void*)l, 16, 0, 0);
}

// ---------------------------------------------------------------------------
// MFMA GEMM core: C(BM x BN) += A(BM x K, ld=lda) * B(BN x K, ld=ldb)^T
// bf16 inputs, fp32 accum. 256 threads = 4 waves arranged WR x WC.
// BK=32 (one 16x16x32 mfma K-slab per step). LDS tiles row-major [rows][32].
// A-frag: lane holds A[m=lane&15][k=quad*8+j]; B-frag: B^T rows same pattern.
// D: n=lane&15, m=quad*4+reg.
// ---------------------------------------------------------------------------
template<int BM, int BN, int WR, int WC, int MI, int NI>
__device__ __forceinline__ void mfma_core(const unsigned short* __restrict__ Ag, int lda,
                                          const unsigned short* __restrict__ Bg, int ldb,
                                          int K, short* As, short* Bs,
                                          f32x4 (&acc)[MI][NI]) {
    const int tid = threadIdx.x;
    const int wave = tid >> 6, lane = tid & 63;
    const int quad = lane >> 4, l16 = lane & 15;
    const int wr = wave / WC, wc = wave % WC;
    constexpr int WMT = BM / WR, WNT = BN / WC;

    for (int k0 = 0; k0 < K; k0 += 32) {
        __syncthreads();                 // previous tile fully consumed
#pragma unroll
        for (int s = 0; s < BM / 64; ++s) {
            const int c = s * 256 + tid;             // chunk: (row=c>>2, kq=c&3)
            gld16(Ag + (size_t)(c >> 2) * lda + k0 + (c & 3) * 8,
                  (char*)As + s * 4096 + wave * 1024);
        }
#pragma unroll
        for (int s = 0; s < BN / 64; ++s) {
            const int c = s * 256 + tid;
            gld16(Bg + (size_t)(c >> 2) * ldb + k0 + (c & 3) * 8,
                  (char*)Bs + s * 4096 + wave * 1024);
        }
        __syncthreads();                 // drains vmcnt -> tile resident

        bf16x8 af[MI], bf[NI];
#pragma unroll
        for (int i = 0; i < MI; ++i)
            af[i] = *(const bf16x8*)&As[(wr * WMT + i * 16 + l16) * 32 + quad * 8];
#pragma unroll
        for (int j = 0; j < NI; ++j)
            bf[j] = *(const bf16x8*)&Bs[(wc * WNT + j * 16 + l16) * 32 + quad * 8];
#pragma unroll
        for (int i = 0; i < MI; ++i)
#pragma unroll
            for (int j = 0; j < NI; ++j)
                acc[i][j] = __builtin_amdgcn_mfma_f32_16x16x32_bf16(af[i], bf[j], acc[i][j], 0, 0, 0);
    }
}

// ---------------------------------------------------------------------------
// fp32 -> bf16 conversion for q, k, and the 4 weight matrices (one dispatch)
// ---------------------------------------------------------------------------
__global__ __launch_bounds__(256) void convert_kernel(
        const float* __restrict__ s0, const float* __restrict__ s1,
        const float* __restrict__ s2, const float* __restrict__ s3,
        const float* __restrict__ s4, const float* __restrict__ s5,
        unsigned short* __restrict__ d0, unsigned short* __restrict__ d1,
        unsigned short* __restrict__ d2, unsigned short* __restrict__ d3,
        unsigned short* __restrict__ d4, unsigned short* __restrict__ d5) {
    const float* s; unsigned short* d; int n;
    switch (blockIdx.y) {
        case 0: s = s0; d = d0; n = NB * LQ * DM; break;
        case 1: s = s1; d = d1; n = NB * LK * DM; break;
        case 2: s = s2; d = d2; n = DM * DM; break;
        case 3: s = s3; d = d3; n = DM * DM; break;
        case 4: s = s4; d = d4; n = DM * DM; break;
        default: s = s5; d = d5; n = DM * DM; break;
    }
    const int i = blockIdx.x * 256 + threadIdx.x;
    if (i * 8 >= n) return;
    const float4* sv = (const float4*)s;
    const float4 a = sv[2 * (size_t)i], b = sv[2 * (size_t)i + 1];
    uint4 o;
    o.x = (unsigned)f2bf(a.x) | ((unsigned)f2bf(a.y) << 16);
    o.y = (unsigned)f2bf(a.z) | ((unsigned)f2bf(a.w) << 16);
    o.z = (unsigned)f2bf(b.x) | ((unsigned)f2bf(b.y) << 16);
    o.w = (unsigned)f2bf(b.z) | ((unsigned)f2bf(b.w) << 16);
    *(uint4*)(d + (size_t)i * 8) = o;
}

// ---------------------------------------------------------------------------
// Projection: C[m,n] = sum_d A[m,d]*W[n,d] (+bias[n]).  MODE 0: bf16 row-major
// store. MODE 1: V-projection, store transposed Vt[b][n][m&511] (bf16).
// ---------------------------------------------------------------------------
template<int MODE>
__global__ __launch_bounds__(256) void proj_mfma(const unsigned short* __restrict__ A,
                                                 const unsigned short* __restrict__ W,
                                                 const float* __restrict__ bias,
                                                 unsigned short* __restrict__ C) {
    __shared__ __align__(16) short As[64 * 32];
    __shared__ __align__(16) short Bs[128 * 32];
    f32x4 acc[4][2];
    const f32x4 zz = {0.f, 0.f, 0.f, 0.f};
#pragma unroll
    for (int i = 0; i < 4; ++i)
#pragma unroll
        for (int j = 0; j < 2; ++j) acc[i][j] = zz;
    const int m0 = blockIdx.x * 64, n0 = blockIdx.y * 128;
    mfma_core<64, 128, 1, 4, 4, 2>(A + (size_t)m0 * DM, DM, W + (size_t)n0 * DM, DM, DM, As, Bs, acc);
    const int tid = threadIdx.x, wave = tid >> 6, lane = tid & 63;
    const int quad = lane >> 4, l16 = lane & 15;
#pragma unroll
    for (int i = 0; i < 4; ++i)
#pragma unroll
        for (int r = 0; r < 4; ++r) {
            const int gm = m0 + i * 16 + quad * 4 + r;
#pragma unroll
            for (int j = 0; j < 2; ++j) {
                const int gn = n0 + wave * 32 + j * 16 + l16;
                float v = acc[i][j][r];
                if (bias) v += bias[gn];
                if (MODE == 0) {
                    C[(size_t)gm * DM + gn] = f2bf(v);
                } else {
                    C[(size_t)(gm >> 9) * (DM * LK) + (size_t)gn * LK + (gm & 511)] = f2bf(v);
                }
            }
        }
}

// Output projection: fp32 store + bias
__global__ __launch_bounds__(256) void outproj_mfma(const unsigned short* __restrict__ A,
                                                    const unsigned short* __restrict__ W,
                                                    const float* __restrict__ bias,
                                                    float* __restrict__ C) {
    __shared__ __align__(16) short As[64 * 32];
    __shared__ __align__(16) short Bs[128 * 32];
    f32x4 acc[4][2];
    const f32x4 zz = {0.f, 0.f, 0.f, 0.f};
#pragma unroll
    for (int i = 0; i < 4; ++i)
#pragma unroll
        for (int j = 0; j < 2; ++j) acc[i][j] = zz;
    const int m0 = blockIdx.x * 64, n0 = blockIdx.y * 128;
    mfma_core<64, 128, 1, 4, 4, 2>(A + (size_t)m0 * DM, DM, W + (size_t)n0 * DM, DM, DM, As, Bs, acc);
    const int tid = threadIdx.x, wave = tid >> 6, lane = tid & 63;
    const int quad = lane >> 4, l16 = lane & 15;
#pragma unroll
    for (int i = 0; i < 4; ++i)
#pragma unroll
        for (int r = 0; r < 4; ++r) {
            const int gm = m0 + i * 16 + quad * 4 + r;
#pragma unroll
            for (int j = 0; j < 2; ++j) {
                const int gn = n0 + wave * 32 + j * 16 + l16;
                C[(size_t)gm * DM + gn] = acc[i][j][r] + bias[gn];
            }
        }
}

// ---------------------------------------------------------------------------
// QK^T per (h,b): raw scores (fp32) -> weights region of d_out
// ---------------------------------------------------------------------------
__global__ __launch_bounds__(256) void qk_mfma(const unsigned short* __restrict__ Qp,
                                               const unsigned short* __restrict__ Kp,
                                               float* __restrict__ Cw) {
    __shared__ __align__(16) short As[128 * 32];
    __shared__ __align__(16) short Bs[128 * 32];
    f32x4 acc[4][4];
    const f32x4 zz = {0.f, 0.f, 0.f, 0.f};
#pragma unroll
    for (int i = 0; i < 4; ++i)
#pragma unroll
        for (int j = 0; j < 4; ++j) acc[i][j] = zz;
    const int z = blockIdx.z, h = z >> 2, b = z & 3;
    const int m0 = blockIdx.x * 128, n0 = blockIdx.y * 128;
    const unsigned short* Ag = Qp + (size_t)(b * LQ + m0) * DM + h * DQ;
    const unsigned short* Bg = Kp + (size_t)(b * LK + n0) * DM + h * DQ;
    mfma_core<128, 128, 2, 2, 4, 4>(Ag, DM, Bg, DM, DQ, As, Bs, acc);
    const int tid = threadIdx.x, wave = tid >> 6, lane = tid & 63;
    const int quad = lane >> 4, l16 = lane & 15;
    const int wr = wave >> 1, wc = wave & 1;
    float* Cz = Cw + (size_t)z * LQ * LK;
#pragma unroll
    for (int i = 0; i < 4; ++i)
#pragma unroll
        for (int r = 0; r < 4; ++r) {
            const int gm = m0 + wr * 64 + i * 16 + quad * 4 + r;
#pragma unroll
            for (int j = 0; j < 4; ++j) {
                const int gn = n0 + wc * 64 + j * 16 + l16;
                Cz[(size_t)gm * LK + gn] = acc[i][j][r];
            }
        }
}

// ---------------------------------------------------------------------------
// s[h,b,q,l] = sum_d Qp[b][q][h*64+d] * b_ks[l][d]
// ---------------------------------------------------------------------------
__global__ __launch_bounds__(64) void rels_kernel(const unsigned short* __restrict__ Qp,
                                                  const float* __restrict__ b_ks,
                                                  float* __restrict__ Sb) {
    __shared__ float qS[DM];
    __shared__ float bS[NL * DQ];
    const int bq = blockIdx.x, b = bq >> 9, q = bq & 511, tid = threadIdx.x;
    const uint4 v = ((const uint4*)(Qp + (size_t)bq * DM))[tid];
    qS[tid * 8 + 0] = bf2f(v.x & 0xffffu); qS[tid * 8 + 1] = bf2f(v.x >> 16);
    qS[tid * 8 + 2] = bf2f(v.y & 0xffffu); qS[tid * 8 + 3] = bf2f(v.y >> 16);
    qS[tid * 8 + 4] = bf2f(v.z & 0xffffu); qS[tid * 8 + 5] = bf2f(v.z >> 16);
    qS[tid * 8 + 6] = bf2f(v.w & 0xffffu); qS[tid * 8 + 7] = bf2f(v.w >> 16);
    const float4* bg = (const float4*)b_ks;
    ((float4*)bS)[tid] = bg[tid];
    ((float4*)bS)[64 + tid] = bg[64 + tid];
    __syncthreads();
    const int h = tid >> 3, l = tid & 7;
    float s = 0.f;
#pragma unroll
    for (int d = 0; d < DQ; ++d) s = fmaf(qS[h * DQ + d], bS[l * DQ + d], s);
    Sb[((size_t)(h * NB + b) * LQ + q) * NL + l] = s;
}

// ---------------------------------------------------------------------------
// Wave-per-head fused rel-score + mask + softmax + t.  512 thr = 8 waves =
// 8 heads of one (b,q) row; lane owns 8 consecutive k.  No LDS, no barriers;
// all reductions are 64-lane shfl_xor butterflies.  em row is L1-served.
// ---------------------------------------------------------------------------
__global__ __launch_bounds__(512) void softmax_kernel(const float* __restrict__ em,
                                                      const float* __restrict__ pad,
                                                      const float* __restrict__ Sb,
                                                      float* __restrict__ weights,
                                                      unsigned short* __restrict__ attn,
                                                      float* __restrict__ Tb) {
    const int tid = threadIdx.x, wave = tid >> 6, lane = tid & 63;
    const int bq = blockIdx.x, b = bq >> 9, q = bq & 511;
    const int z = wave * NB + b;

    float4 ev[16];   // em[bq][k0..k0+7][0..7], 64 contiguous floats per lane
    const float4* eg = (const float4*)(em + (size_t)bq * (LK * NL) + lane * 64);
#pragma unroll
    for (int t = 0; t < 16; ++t) ev[t] = eg[t];

    float sv[8];
    const float* sp = Sb + ((size_t)z * LQ + q) * NL;
#pragma unroll
    for (int l = 0; l < 8; ++l) sv[l] = sp[l];

    const float4* pg = (const float4*)(pad + (size_t)bq * LK + lane * 8);
    const float4 p0 = pg[0], p1 = pg[1];
    const float padv[8] = {p0.x, p0.y, p0.z, p0.w, p1.x, p1.y, p1.z, p1.w};

    float* wp = weights + ((size_t)z * LQ + q) * LK + lane * 8;
    const float4 w0 = ((const float4*)wp)[0], w1 = ((const float4*)wp)[1];
    const float qk8[8] = {w0.x, w0.y, w0.z, w0.w, w1.x, w1.y, w1.z, w1.w};

    float wv8[8], m8[8];
#pragma unroll
    for (int j = 0; j < 8; ++j) {
        const float4 a = ev[2 * j], c = ev[2 * j + 1];
        const float rel = a.x * sv[0] + a.y * sv[1] + a.z * sv[2] + a.w * sv[3]
                        + c.x * sv[4] + c.y * sv[5] + c.z * sv[6] + c.w * sv[7];
        const float es = ((a.x + a.y) + (a.z + a.w)) + ((c.x + c.y) + (c.z + c.w));
        const float wv = (qk8[j] + rel) * 0.125f;
        wv8[j] = wv;
        m8[j] = ((es + 1.0f - padv[j]) == 0.0f) ? -__builtin_inff() : wv;
    }
    const float4 o0 = {wv8[0], wv8[1], wv8[2], wv8[3]};
    const float4 o1 = {wv8[4], wv8[5], wv8[6], wv8[7]};
    ((float4*)wp)[0] = o0; ((float4*)wp)[1] = o1;      // pre-mask weights output

    float mx = m8[0];
#pragma unroll
    for (int j = 1; j < 8; ++j) mx = fmaxf(mx, m8[j]);
#pragma unroll
    for (int o = 1; o < 64; o <<= 1) mx = fmaxf(mx, __shfl_xor(mx, o, 64));

    float e8[8], ss = 0.f;
#pragma unroll
    for (int j = 0; j < 8; ++j) { e8[j] = __expf(m8[j] - mx); ss += e8[j]; }
#pragma unroll
    for (int o = 1; o < 64; o <<= 1) ss += __shfl_xor(ss, o, 64);
    const float inv = 1.0f / ss;

    float tl[8] = {0.f, 0.f, 0.f, 0.f, 0.f, 0.f, 0.f, 0.f};
    unsigned short rr[8];
#pragma unroll
    for (int j = 0; j < 8; ++j) {
        const float a_ = e8[j] * inv;                  // masked -> exactly 0
        rr[j] = f2bf(a_);
        const float4 a = ev[2 * j], c = ev[2 * j + 1];
        tl[0] = fmaf(a_, a.x, tl[0]); tl[1] = fmaf(a_, a.y, tl[1]);
        tl[2] = fmaf(a_, a.z, tl[2]); tl[3] = fmaf(a_, a.w, tl[3]);
        tl[4] = fmaf(a_, c.x, tl[4]); tl[5] = fmaf(a_, c.y, tl[5]);
        tl[6] = fmaf(a_, c.z, tl[6]); tl[7] = fmaf(a_, c.w, tl[7]);
    }
    uint4 ov;
    ov.x = (unsigned)rr[0] | ((unsigned)rr[1] << 16);
    ov.y = (unsigned)rr[2] | ((unsigned)rr[3] << 16);
    ov.z = (unsigned)rr[4] | ((unsigned)rr[5] << 16);
    ov.w = (unsigned)rr[6] | ((unsigned)rr[7] << 16);
    *(uint4*)(attn + ((size_t)z * LQ + q) * LK + lane * 8) = ov;

#pragma unroll
    for (int o = 1; o < 64; o <<= 1)
#pragma unroll
        for (int l = 0; l < 8; ++l) tl[l] += __shfl_xor(tl[l], o, 64);
    if (lane == 0) {
        float* tp = Tb + ((size_t)z * LQ + q) * NL;
#pragma unroll
        for (int l = 0; l < 8; ++l) tp[l] = tl[l];
    }
}

// ---------------------------------------------------------------------------
// qv + qvr:  Hb[b][q][h*64+d] = sum_k attn*Vt + sum_l t[l]*b_vs[l][d]
// ---------------------------------------------------------------------------
__global__ __launch_bounds__(256) void qv_mfma(const unsigned short* __restrict__ Attn,
                                               const unsigned short* __restrict__ Vt,
                                               const float* __restrict__ Tb,
                                               const float* __restrict__ b_vs,
                                               unsigned short* __restrict__ Hb) {
    __shared__ __align__(16) short As[128 * 32];
    __shared__ __align__(16) short Bs[64 * 32];
    f32x4 acc[4][2];
    const f32x4 zz = {0.f, 0.f, 0.f, 0.f};
#pragma unroll
    for (int i = 0; i < 4; ++i)
#pragma unroll
        for (int j = 0; j < 2; ++j) acc[i][j] = zz;
    const int z = blockIdx.z, h = z >> 2, b = z & 3;
    const int m0 = blockIdx.x * 128;
    const unsigned short* Ag = Attn + (size_t)z * LQ * LK + (size_t)m0 * LK;
    const unsigned short* Bg = Vt + (size_t)b * (DM * LK) + (size_t)(h * DQ) * LK;
    mfma_core<128, 64, 2, 2, 4, 2>(Ag, LK, Bg, LK, LK, As, Bs, acc);
    const int tid = threadIdx.x, wave = tid >> 6, lane = tid & 63;
    const int quad = lane >> 4, l16 = lane & 15;
    const int wr = wave >> 1, wc = wave & 1;
    float bvv[2][8];
#pragma unroll
    for (int j = 0; j < 2; ++j)
#pragma unroll
        for (int l = 0; l < 8; ++l) bvv[j][l] = b_vs[l * DQ + wc * 32 + j * 16 + l16];
#pragma unroll
    for (int i = 0; i < 4; ++i)
#pragma unroll
        for (int r = 0; r < 4; ++r) {
            const int qrow = m0 + wr * 64 + i * 16 + quad * 4 + r;
            const float* t8 = Tb + ((size_t)z * LQ + qrow) * NL;
            float t[8];
#pragma unroll
            for (int l = 0; l < 8; ++l) t[l] = t8[l];
#pragma unroll
            for (int j = 0; j < 2; ++j) {
                const int d = wc * 32 + j * 16 + l16;
                float qvr = 0.f;
#pragma unroll
                for (int l = 0; l < 8; ++l) qvr = fmaf(t[l], bvv[j][l], qvr);
                Hb[(size_t)(b * LQ + qrow) * DM + h * DQ + d] = f2bf(acc[i][j][r] + qvr);
            }
        }
}

// ---------------------------------------------------------------------------
extern "C" void kernel_launch(void* const* d_in, const int* in_sizes, int n_in,
                              void* d_out, int out_size, void* d_ws, size_t ws_size,
                              hipStream_t stream) {
    const float* q     = (const float*)d_in[0];
    const float* k     = (const float*)d_in[1];
    const float* em    = (const float*)d_in[2];
    const float* pad   = (const float*)d_in[3];
    const float* w_q_w = (const float*)d_in[4];
    const float* w_q_b = (const float*)d_in[5];
    const float* w_k   = (const float*)d_in[6];
    const float* w_v   = (const float*)d_in[7];
    const float* w_h_w = (const float*)d_in[8];
    const float* w_h_b = (const float*)d_in[9];
    const float* b_ks  = (const float*)d_in[10];
    const float* b_vs  = (const float*)d_in[11];

    float* out     = (float*)d_out;                       // (B, LQ, DM) fp32
    float* weights = out + (size_t)NB * LQ * DM;          // (H*B, LQ, LK) fp32

    char* ws = (char*)d_ws;                               // byte offsets (all 16B-aligned)
    unsigned short* qbf = (unsigned short*)(ws + 0);          // 2 MB
    unsigned short* kbf = (unsigned short*)(ws + 2097152);    // 2 MB
    unsigned short* wqb = (unsigned short*)(ws + 4194304);    // 512 KB
    unsigned short* wkb = (unsigned short*)(ws + 4718592);
    unsigned short* wvb = (unsigned short*)(ws + 5242880);
    unsigned short* whb = (unsigned short*)(ws + 5767168);
    unsigned short* Qp  = (unsigned short*)(ws + 6291456);    // 2 MB
    unsigned short* Kp  = (unsigned short*)(ws + 8388608);    // 2 MB
    unsigned short* Vt  = (unsigned short*)(ws + 10485760);   // 2 MB
    unsigned short* Hb  = (unsigned short*)(ws + 12582912);   // 2 MB
    unsigned short* Att = (unsigned short*)(ws + 14680064);   // 16 MB
    float*          Sb  = (float*)(ws + 31457280);            // 512 KB
    float*          Tb  = (float*)(ws + 31981568);            // 512 KB

    convert_kernel<<<dim3(512, 6), 256, 0, stream>>>(q, k, w_q_w, w_k, w_v, w_h_w,
                                                     qbf, kbf, wqb, wkb, wvb, whb);
    proj_mfma<0><<<dim3(32, 4), 256, 0, stream>>>(qbf, wqb, w_q_b, Qp);
    proj_mfma<0><<<dim3(32, 4), 256, 0, stream>>>(kbf, wkb, nullptr, Kp);
    proj_mfma<1><<<dim3(32, 4), 256, 0, stream>>>(kbf, wvb, nullptr, Vt);
    qk_mfma<<<dim3(4, 4, 32), 256, 0, stream>>>(Qp, Kp, weights);
    rels_kernel<<<dim3(NB * LQ), dim3(64), 0, stream>>>(Qp, b_ks, Sb);
    softmax_kernel<<<dim3(NB * LQ), dim3(512), 0, stream>>>(em, pad, Sb, weights, Att, Tb);
    qv_mfma<<<dim3(4, 1, 32), 256, 0, stream>>>(Att, Vt, Tb, b_vs, Hb);
    outproj_mfma<<<dim3(32, 4), 256, 0, stream>>>(Hb, whb, w_h_b, out);
}

// Round 3
// 173.268 us; speedup vs baseline: 2.0137x; 1.2438x over previous
//
#include <hip/hip_runtime.h>
#include <math.h>

#define NB 4
#define LQ 512
#define LK 512
#define DM 512
#define NH 8
#define DQ 64
#define NL 8

typedef short bf16x8 __attribute__((ext_vector_type(8)));
typedef float f32x4 __attribute__((ext_vector_type(4)));

__device__ __forceinline__ unsigned short f2bf(float x) {
    unsigned u = __float_as_uint(x);
    u += 0x7fff + ((u >> 16) & 1);          // RNE
    return (unsigned short)(u >> 16);
}
__device__ __forceinline__ float bf2f(unsigned x) {
    return __uint_as_float(x << 16);
}

// async global->LDS, 16B per lane. LDS dest is wave-uniform base + lane*16.
__device__ __forceinline__ void gld16(const void* g, void* l) {
    __builtin_amdgcn_global_load_lds(
        (const __attribute__((address_space(1))) void*)g,
        (__attribute__((address_space(3))) void*)l, 16, 0, 0);
}

// ---------------------------------------------------------------------------
// MFMA GEMM core: C(BM x BN) += A(BM x K, ld=lda) * B(BN x K, ld=ldb)^T
// bf16 in, fp32 accum. 256 threads = 4 waves arranged WR x WC.
// BK=32. LDS tiles row-major [rows][32] bf16.
// ---------------------------------------------------------------------------
template<int BM, int BN, int WR, int WC, int MI, int NI>
__device__ __forceinline__ void mfma_core(const unsigned short* __restrict__ Ag, int lda,
                                          const unsigned short* __restrict__ Bg, int ldb,
                                          int K, short* As, short* Bs,
                                          f32x4 (&acc)[MI][NI]) {
    const int tid = threadIdx.x;
    const int wave = tid >> 6, lane = tid & 63;
    const int quad = lane >> 4, l16 = lane & 15;
    const int wr = wave / WC, wc = wave % WC;
    constexpr int WMT = BM / WR, WNT = BN / WC;

    for (int k0 = 0; k0 < K; k0 += 32) {
        __syncthreads();                 // previous tile fully consumed
#pragma unroll
        for (int s = 0; s < BM / 64; ++s) {
            const int c = s * 256 + tid;             // chunk: (row=c>>2, kq=c&3)
            gld16(Ag + (size_t)(c >> 2) * lda + k0 + (c & 3) * 8,
                  (char*)As + s * 4096 + wave * 1024);
        }
#pragma unroll
        for (int s = 0; s < BN / 64; ++s) {
            const int c = s * 256 + tid;
            gld16(Bg + (size_t)(c >> 2) * ldb + k0 + (c & 3) * 8,
                  (char*)Bs + s * 4096 + wave * 1024);
        }
        __syncthreads();                 // drains vmcnt -> tile resident

        bf16x8 af[MI], bf[NI];
#pragma unroll
        for (int i = 0; i < MI; ++i)
            af[i] = *(const bf16x8*)&As[(wr * WMT + i * 16 + l16) * 32 + quad * 8];
#pragma unroll
        for (int j = 0; j < NI; ++j)
            bf[j] = *(const bf16x8*)&Bs[(wc * WNT + j * 16 + l16) * 32 + quad * 8];
#pragma unroll
        for (int i = 0; i < MI; ++i)
#pragma unroll
            for (int j = 0; j < NI; ++j)
                acc[i][j] = __builtin_amdgcn_mfma_f32_16x16x32_bf16(af[i], bf[j], acc[i][j], 0, 0, 0);
    }
}

// ---------------------------------------------------------------------------
// fp32 -> bf16 conversion for q, k, and the 4 weight matrices (one dispatch)
// ---------------------------------------------------------------------------
__global__ __launch_bounds__(256) void convert_kernel(
        const float* __restrict__ s0, const float* __restrict__ s1,
        const float* __restrict__ s2, const float* __restrict__ s3,
        const float* __restrict__ s4, const float* __restrict__ s5,
        unsigned short* __restrict__ d0, unsigned short* __restrict__ d1,
        unsigned short* __restrict__ d2, unsigned short* __restrict__ d3,
        unsigned short* __restrict__ d4, unsigned short* __restrict__ d5) {
    const float* s; unsigned short* d; int n;
    switch (blockIdx.y) {
        case 0: s = s0; d = d0; n = NB * LQ * DM; break;
        case 1: s = s1; d = d1; n = NB * LK * DM; break;
        case 2: s = s2; d = d2; n = DM * DM; break;
        case 3: s = s3; d = d3; n = DM * DM; break;
        case 4: s = s4; d = d4; n = DM * DM; break;
        default: s = s5; d = d5; n = DM * DM; break;
    }
    const int i = blockIdx.x * 256 + threadIdx.x;
    if (i * 8 >= n) return;
    const float4* sv = (const float4*)s;
    const float4 a = sv[2 * (size_t)i], b = sv[2 * (size_t)i + 1];
    uint4 o;
    o.x = (unsigned)f2bf(a.x) | ((unsigned)f2bf(a.y) << 16);
    o.y = (unsigned)f2bf(a.z) | ((unsigned)f2bf(a.w) << 16);
    o.z = (unsigned)f2bf(b.x) | ((unsigned)f2bf(b.y) << 16);
    o.w = (unsigned)f2bf(b.z) | ((unsigned)f2bf(b.w) << 16);
    *(uint4*)(d + (size_t)i * 8) = o;
}

// ---------------------------------------------------------------------------
// All three input projections in one dispatch (z: 0=Q, 1=K, 2=V-transposed).
// 64x64 tiles -> grid (32, 8, 3) = 768 blocks.
// ---------------------------------------------------------------------------
__global__ __launch_bounds__(256) void proj_all(const unsigned short* __restrict__ qbf,
                                                const unsigned short* __restrict__ kbf,
                                                const unsigned short* __restrict__ wqb,
                                                const unsigned short* __restrict__ wkb,
                                                const unsigned short* __restrict__ wvb,
                                                const float* __restrict__ w_q_b,
                                                unsigned short* __restrict__ Qp,
                                                unsigned short* __restrict__ Kp,
                                                unsigned short* __restrict__ Vt) {
    __shared__ __align__(16) short As[64 * 32];
    __shared__ __align__(16) short Bs[64 * 32];
    const unsigned short* A; const unsigned short* W; const float* bias;
    unsigned short* C; int mode;
    switch (blockIdx.z) {
        case 0:  A = qbf; W = wqb; bias = w_q_b; C = Qp; mode = 0; break;
        case 1:  A = kbf; W = wkb; bias = nullptr; C = Kp; mode = 0; break;
        default: A = kbf; W = wvb; bias = nullptr; C = Vt; mode = 1; break;
    }
    f32x4 acc[2][2];
    const f32x4 zz = {0.f, 0.f, 0.f, 0.f};
#pragma unroll
    for (int i = 0; i < 2; ++i)
#pragma unroll
        for (int j = 0; j < 2; ++j) acc[i][j] = zz;
    const int m0 = blockIdx.x * 64, n0 = blockIdx.y * 64;
    mfma_core<64, 64, 2, 2, 2, 2>(A + (size_t)m0 * DM, DM, W + (size_t)n0 * DM, DM, DM, As, Bs, acc);
    const int tid = threadIdx.x, wave = tid >> 6, lane = tid & 63;
    const int quad = lane >> 4, l16 = lane & 15;
    const int wr = wave >> 1, wc = wave & 1;
#pragma unroll
    for (int i = 0; i < 2; ++i)
#pragma unroll
        for (int r = 0; r < 4; ++r) {
            const int gm = m0 + wr * 32 + i * 16 + quad * 4 + r;
#pragma unroll
            for (int j = 0; j < 2; ++j) {
                const int gn = n0 + wc * 32 + j * 16 + l16;
                float v = acc[i][j][r];
                if (bias) v += bias[gn];
                if (mode == 0) C[(size_t)gm * DM + gn] = f2bf(v);
                else C[(size_t)(gm >> 9) * (DM * LK) + (size_t)gn * LK + (gm & 511)] = f2bf(v);
            }
        }
}

// ---------------------------------------------------------------------------
// QK^T per (h,b): raw scores written as bf16 to workspace Sc.
// 64x64 tiles -> grid (8, 8, 32) = 2048 blocks.
// ---------------------------------------------------------------------------
__global__ __launch_bounds__(256) void qk_mfma(const unsigned short* __restrict__ Qp,
                                               const unsigned short* __restrict__ Kp,
                                               unsigned short* __restrict__ Sc) {
    __shared__ __align__(16) short As[64 * 32];
    __shared__ __align__(16) short Bs[64 * 32];
    f32x4 acc[2][2];
    const f32x4 zz = {0.f, 0.f, 0.f, 0.f};
#pragma unroll
    for (int i = 0; i < 2; ++i)
#pragma unroll
        for (int j = 0; j < 2; ++j) acc[i][j] = zz;
    const int z = blockIdx.z, h = z >> 2, b = z & 3;
    const int m0 = blockIdx.x * 64, n0 = blockIdx.y * 64;
    const unsigned short* Ag = Qp + (size_t)(b * LQ + m0) * DM + h * DQ;
    const unsigned short* Bg = Kp + (size_t)(b * LK + n0) * DM + h * DQ;
    mfma_core<64, 64, 2, 2, 2, 2>(Ag, DM, Bg, DM, DQ, As, Bs, acc);
    const int tid = threadIdx.x, wave = tid >> 6, lane = tid & 63;
    const int quad = lane >> 4, l16 = lane & 15;
    const int wr = wave >> 1, wc = wave & 1;
    unsigned short* Cz = Sc + (size_t)z * LQ * LK;
#pragma unroll
    for (int i = 0; i < 2; ++i)
#pragma unroll
        for (int r = 0; r < 4; ++r) {
            const int gm = m0 + wr * 32 + i * 16 + quad * 4 + r;
#pragma unroll
            for (int j = 0; j < 2; ++j) {
                const int gn = n0 + wc * 32 + j * 16 + l16;
                Cz[(size_t)gm * LK + gn] = f2bf(acc[i][j][r]);
            }
        }
}

// ---------------------------------------------------------------------------
// Wave-per-head fused rel-score + mask + softmax + t.  512 thr = 8 waves =
// 8 heads of one (b,q) row.  Lane owns k = lane + 64*j (interleaved ->
// every global access unit-stride across lanes).  s[h,l] computed in-wave
// by shuffle reduction (no Sb round-trip).  No LDS, no barriers.
// ---------------------------------------------------------------------------
__global__ __launch_bounds__(512) void softmax_kernel(const float* __restrict__ em,
                                                      const float* __restrict__ pad,
                                                      const unsigned short* __restrict__ Qp,
                                                      const float* __restrict__ b_ks,
                                                      const unsigned short* __restrict__ Sc,
                                                      float* __restrict__ weights,
                                                      unsigned short* __restrict__ attn,
                                                      float* __restrict__ Tb) {
    const int tid = threadIdx.x, wave = tid >> 6, lane = tid & 63;
    const int bq = blockIdx.x, b = bq >> 9, q = bq & 511;
    const int h = wave, z = h * NB + b;

    // s[l] = sum_d Qp[bq][h*64+d] * b_ks[l][d], lane = d, butterfly-reduce
    const float qd = bf2f(Qp[(size_t)bq * DM + h * DQ + lane]);
    float sv[NL];
#pragma unroll
    for (int l = 0; l < NL; ++l) {
        float p = qd * b_ks[l * DQ + lane];
#pragma unroll
        for (int o = 1; o < 64; o <<= 1) p += __shfl_xor(p, o, 64);
        sv[l] = p;
    }

    // em[bq][k][0..7] for k = lane + 64j  (32B/lane, unit-stride across lanes)
    float4 ev[16];
    const float* eb = em + (size_t)bq * (LK * NL);
#pragma unroll
    for (int j = 0; j < 8; ++j) {
        const int k = lane + 64 * j;
        ev[2 * j]     = *(const float4*)(eb + k * 8);
        ev[2 * j + 1] = *(const float4*)(eb + k * 8 + 4);
    }
    float padv[8];
#pragma unroll
    for (int j = 0; j < 8; ++j) padv[j] = pad[(size_t)bq * LK + lane + 64 * j];
    const unsigned short* sp = Sc + ((size_t)z * LQ + q) * LK;
    float qk8[8];
#pragma unroll
    for (int j = 0; j < 8; ++j) qk8[j] = bf2f(sp[lane + 64 * j]);

    const size_t rowbase = ((size_t)z * LQ + q) * LK;
    float wv8[8], m8[8];
#pragma unroll
    for (int j = 0; j < 8; ++j) {
        const float4 a = ev[2 * j], c = ev[2 * j + 1];
        const float rel = a.x * sv[0] + a.y * sv[1] + a.z * sv[2] + a.w * sv[3]
                        + c.x * sv[4] + c.y * sv[5] + c.z * sv[6] + c.w * sv[7];
        const float es = ((a.x + a.y) + (a.z + a.w)) + ((c.x + c.y) + (c.z + c.w));
        const float wv = (qk8[j] + rel) * 0.125f;
        wv8[j] = wv;
        m8[j] = ((es + 1.0f - padv[j]) == 0.0f) ? -__builtin_inff() : wv;
        weights[rowbase + lane + 64 * j] = wv;          // pre-mask weights output
    }

    float mx = m8[0];
#pragma unroll
    for (int j = 1; j < 8; ++j) mx = fmaxf(mx, m8[j]);
#pragma unroll
    for (int o = 1; o < 64; o <<= 1) mx = fmaxf(mx, __shfl_xor(mx, o, 64));

    float e8[8], ss = 0.f;
#pragma unroll
    for (int j = 0; j < 8; ++j) { e8[j] = __expf(m8[j] - mx); ss += e8[j]; }
#pragma unroll
    for (int o = 1; o < 64; o <<= 1) ss += __shfl_xor(ss, o, 64);
    const float inv = 1.0f / ss;

    float tl[NL] = {0.f, 0.f, 0.f, 0.f, 0.f, 0.f, 0.f, 0.f};
#pragma unroll
    for (int j = 0; j < 8; ++j) {
        const float a_ = e8[j] * inv;                   // masked -> exactly 0
        attn[rowbase + lane + 64 * j] = f2bf(a_);
        const float4 a = ev[2 * j], c = ev[2 * j + 1];
        tl[0] = fmaf(a_, a.x, tl[0]); tl[1] = fmaf(a_, a.y, tl[1]);
        tl[2] = fmaf(a_, a.z, tl[2]); tl[3] = fmaf(a_, a.w, tl[3]);
        tl[4] = fmaf(a_, c.x, tl[4]); tl[5] = fmaf(a_, c.y, tl[5]);
        tl[6] = fmaf(a_, c.z, tl[6]); tl[7] = fmaf(a_, c.w, tl[7]);
    }
#pragma unroll
    for (int o = 1; o < 64; o <<= 1)
#pragma unroll
        for (int l = 0; l < NL; ++l) tl[l] += __shfl_xor(tl[l], o, 64);
    if (lane == 0) {
        float* tp = Tb + ((size_t)z * LQ + q) * NL;
#pragma unroll
        for (int l = 0; l < NL; ++l) tp[l] = tl[l];
    }
}

// ---------------------------------------------------------------------------
// qv + qvr:  Hb[b][q][h*64+d] = sum_k attn*Vt + sum_l t[l]*b_vs[l][d]
// 64x64 tiles -> grid (8, 1, 32) = 256 blocks.
// ---------------------------------------------------------------------------
__global__ __launch_bounds__(256) void qv_mfma(const unsigned short* __restrict__ Attn,
                                               const unsigned short* __restrict__ Vt,
                                               const float* __restrict__ Tb,
                                               const float* __restrict__ b_vs,
                                               unsigned short* __restrict__ Hb) {
    __shared__ __align__(16) short As[64 * 32];
    __shared__ __align__(16) short Bs[64 * 32];
    f32x4 acc[2][2];
    const f32x4 zz = {0.f, 0.f, 0.f, 0.f};
#pragma unroll
    for (int i = 0; i < 2; ++i)
#pragma unroll
        for (int j = 0; j < 2; ++j) acc[i][j] = zz;
    const int z = blockIdx.z, h = z >> 2, b = z & 3;
    const int m0 = blockIdx.x * 64;
    const unsigned short* Ag = Attn + (size_t)z * LQ * LK + (size_t)m0 * LK;
    const unsigned short* Bg = Vt + (size_t)b * (DM * LK) + (size_t)(h * DQ) * LK;
    mfma_core<64, 64, 2, 2, 2, 2>(Ag, LK, Bg, LK, LK, As, Bs, acc);
    const int tid = threadIdx.x, wave = tid >> 6, lane = tid & 63;
    const int quad = lane >> 4, l16 = lane & 15;
    const int wr = wave >> 1, wc = wave & 1;
    float bvv[2][NL];
#pragma unroll
    for (int j = 0; j < 2; ++j)
#pragma unroll
        for (int l = 0; l < NL; ++l) bvv[j][l] = b_vs[l * DQ + wc * 32 + j * 16 + l16];
#pragma unroll
    for (int i = 0; i < 2; ++i)
#pragma unroll
        for (int r = 0; r < 4; ++r) {
            const int qrow = m0 + wr * 32 + i * 16 + quad * 4 + r;
            const float* t8 = Tb + ((size_t)z * LQ + qrow) * NL;
            float t[NL];
#pragma unroll
            for (int l = 0; l < NL; ++l) t[l] = t8[l];
#pragma unroll
            for (int j = 0; j < 2; ++j) {
                const int d = wc * 32 + j * 16 + l16;
                float qvr = 0.f;
#pragma unroll
                for (int l = 0; l < NL; ++l) qvr = fmaf(t[l], bvv[j][l], qvr);
                Hb[(size_t)(b * LQ + qrow) * DM + h * DQ + d] = f2bf(acc[i][j][r] + qvr);
            }
        }
}

// ---------------------------------------------------------------------------
// Output projection: fp32 store + bias.  64x64 tiles -> grid (32, 8).
// ---------------------------------------------------------------------------
__global__ __launch_bounds__(256) void outproj_mfma(const unsigned short* __restrict__ A,
                                                    const unsigned short* __restrict__ W,
                                                    const float* __restrict__ bias,
                                                    float* __restrict__ C) {
    __shared__ __align__(16) short As[64 * 32];
    __shared__ __align__(16) short Bs[64 * 32];
    f32x4 acc[2][2];
    const f32x4 zz = {0.f, 0.f, 0.f, 0.f};
#pragma unroll
    for (int i = 0; i < 2; ++i)
#pragma unroll
        for (int j = 0; j < 2; ++j) acc[i][j] = zz;
    const int m0 = blockIdx.x * 64, n0 = blockIdx.y * 64;
    mfma_core<64, 64, 2, 2, 2, 2>(A + (size_t)m0 * DM, DM, W + (size_t)n0 * DM, DM, DM, As, Bs, acc);
    const int tid = threadIdx.x, wave = tid >> 6, lane = tid & 63;
    const int quad = lane >> 4, l16 = lane & 15;
    const int wr = wave >> 1, wc = wave & 1;
#pragma unroll
    for (int i = 0; i < 2; ++i)
#pragma unroll
        for (int r = 0; r < 4; ++r) {
            const int gm = m0 + wr * 32 + i * 16 + quad * 4 + r;
#pragma unroll
            for (int j = 0; j < 2; ++j) {
                const int gn = n0 + wc * 32 + j * 16 + l16;
                C[(size_t)gm * DM + gn] = acc[i][j][r] + bias[gn];
            }
        }
}

// ---------------------------------------------------------------------------
extern "C" void kernel_launch(void* const* d_in, const int* in_sizes, int n_in,
                              void* d_out, int out_size, void* d_ws, size_t ws_size,
                              hipStream_t stream) {
    const float* q     = (const float*)d_in[0];
    const float* k     = (const float*)d_in[1];
    const float* em    = (const float*)d_in[2];
    const float* pad   = (const float*)d_in[3];
    const float* w_q_w = (const float*)d_in[4];
    const float* w_q_b = (const float*)d_in[5];
    const float* w_k   = (const float*)d_in[6];
    const float* w_v   = (const float*)d_in[7];
    const float* w_h_w = (const float*)d_in[8];
    const float* w_h_b = (const float*)d_in[9];
    const float* b_ks  = (const float*)d_in[10];
    const float* b_vs  = (const float*)d_in[11];

    float* out     = (float*)d_out;                       // (B, LQ, DM) fp32
    float* weights = out + (size_t)NB * LQ * DM;          // (H*B, LQ, LK) fp32

    char* ws = (char*)d_ws;                               // byte offsets (16B-aligned)
    unsigned short* qbf = (unsigned short*)(ws + 0);          // 2 MB
    unsigned short* kbf = (unsigned short*)(ws + 2097152);    // 2 MB
    unsigned short* wqb = (unsigned short*)(ws + 4194304);    // 512 KB
    unsigned short* wkb = (unsigned short*)(ws + 4718592);
    unsigned short* wvb = (unsigned short*)(ws + 5242880);
    unsigned short* whb = (unsigned short*)(ws + 5767168);
    unsigned short* Qp  = (unsigned short*)(ws + 6291456);    // 2 MB
    unsigned short* Kp  = (unsigned short*)(ws + 8388608);    // 2 MB
    unsigned short* Vt  = (unsigned short*)(ws + 10485760);   // 2 MB
    unsigned short* Hb  = (unsigned short*)(ws + 12582912);   // 2 MB
    unsigned short* Att = (unsigned short*)(ws + 14680064);   // 16 MB
    unsigned short* Sc  = (unsigned short*)(ws + 31457280);   // 16 MB bf16 scores
    float*          Tb  = (float*)(ws + 48234496);            // 512 KB

    convert_kernel<<<dim3(512, 6), 256, 0, stream>>>(q, k, w_q_w, w_k, w_v, w_h_w,
                                                     qbf, kbf, wqb, wkb, wvb, whb);
    proj_all<<<dim3(32, 8, 3), 256, 0, stream>>>(qbf, kbf, wqb, wkb, wvb, w_q_b, Qp, Kp, Vt);
    qk_mfma<<<dim3(8, 8, 32), 256, 0, stream>>>(Qp, Kp, Sc);
    softmax_kernel<<<dim3(NB * LQ), dim3(512), 0, stream>>>(em, pad, Qp, b_ks, Sc,
                                                            weights, Att, Tb);
    qv_mfma<<<dim3(8, 1, 32), 256, 0, stream>>>(Att, Vt, Tb, b_vs, Hb);
    outproj_mfma<<<dim3(32, 8), 256, 0, stream>>>(Hb, whb, w_h_b, out);
}